// Round 7
// baseline (516.473 us; speedup 1.0000x reference)
//
#include <hip/hip_runtime.h>
#include <hip/hip_bf16.h>

typedef float f32x4 __attribute__((ext_vector_type(4)));
typedef short bf16x8 __attribute__((ext_vector_type(8)));

#define NB 4
#define NC 64
#define NH 128
#define NW 128
#define NN 4096
#define BN_EPS_C 1e-5f

__device__ __forceinline__ void gld16(const void* g, void* l) {
    __builtin_amdgcn_global_load_lds((const __attribute__((address_space(1))) void*)g,
                                     (__attribute__((address_space(3))) void*)l, 16, 0, 0);
}
__device__ __forceinline__ unsigned pk2(float a, float b) {
    __hip_bfloat16 x = __float2bfloat16(a), y = __float2bfloat16(b);
    return (unsigned)*(unsigned short*)&x | ((unsigned)*(unsigned short*)&y << 16);
}

// ------- weight repack: cw[oc][ic][3][3] -> W3[ocg16][ic64][oc4*12+kk] (192B/entry) -------
__global__ __launch_bounds__(256) void k_wrep(const float* __restrict__ cw, float* __restrict__ W3)
{
    int idx = blockIdx.x * 256 + threadIdx.x;   // 16*64*36 = 36864
    if (idx >= 16 * 64 * 36) return;
    int oq = idx / (64 * 36);
    int rem = idx - oq * (64 * 36);
    int ic = rem / 36;
    int j = rem - ic * 36;
    int oc4 = j / 9, kk = j - oc4 * 9;
    W3[((size_t)oq * 64 + ic) * 48 + oc4 * 12 + kk] = cw[(((size_t)(oq * 4 + oc4)) * 64 + ic) * 9 + kk];
}

// ---- conv3x3 s2 p1 + bias + BN + ReLU -> xg[b][n][c]; wave=4 oc, 1024 blocks ----
__global__ __launch_bounds__(256) void k_conv(
    const float* __restrict__ x, const float* __restrict__ W3, const float* __restrict__ cb,
    const float* __restrict__ bng, const float* __restrict__ bnb, const float* __restrict__ bnm,
    const float* __restrict__ bnv, float* __restrict__ xg)
{
    int oh = blockIdx.x, quad = blockIdx.y, b = blockIdx.z;
    int tid = threadIdx.x;
    int ow = tid & 63;
    int w = __builtin_amdgcn_readfirstlane(tid >> 6);
    int ocg = quad * 4 + w;            // 0..15, wave-uniform
    float acc[4] = {0.f, 0.f, 0.f, 0.f};
    const float* xb = x + (size_t)b * NC * NH * NW;
    const float* wbase = W3 + (size_t)ocg * 64 * 48;
    int ih0 = 2 * oh - 1;
    for (int ic = 0; ic < 64; ++ic) {
        const float* xr = xb + (size_t)ic * (NH * NW);
        float v00, v01, v02, v10, v11, v12, v20, v21, v22;
        if (ih0 < 0) { v00 = v01 = v02 = 0.f; }
        else {
            const float* p = xr + ih0 * NW + 2 * ow;
            float2 t = *(const float2*)p;
            v01 = t.x; v02 = t.y;
            v00 = (ow == 0) ? 0.f : p[-1];
        }
        { const float* p = xr + (ih0 + 1) * NW + 2 * ow; float2 t = *(const float2*)p; v11 = t.x; v12 = t.y; v10 = (ow == 0) ? 0.f : p[-1]; }
        { const float* p = xr + (ih0 + 2) * NW + 2 * ow; float2 t = *(const float2*)p; v21 = t.x; v22 = t.y; v20 = (ow == 0) ? 0.f : p[-1]; }
        const float* wp = wbase + ic * 48;   // uniform -> s_loads
#pragma unroll
        for (int j = 0; j < 4; ++j) {
            const float* wj = wp + j * 12;
            acc[j] += wj[0] * v00 + wj[1] * v01 + wj[2] * v02
                    + wj[3] * v10 + wj[4] * v11 + wj[5] * v12
                    + wj[6] * v20 + wj[7] * v21 + wj[8] * v22;
        }
    }
    int n = oh * 64 + ow;
    int oc0 = ocg * 4;
    f32x4 r;
#pragma unroll
    for (int j = 0; j < 4; ++j) {
        int oc = oc0 + j;
        float s = bng[oc] * rsqrtf(bnv[oc] + BN_EPS_C);
        float y = (acc[j] + cb[oc] - bnm[oc]) * s + bnb[oc];
        r[j] = fmaxf(y, 0.f);
    }
    *(f32x4*)(xg + ((size_t)b * NN + n) * 64 + oc0) = r;
}

// ------- sobel |gx|,|gy| over (N, c) image per batch -> split bf16 hi/lo -------
__global__ __launch_bounds__(256) void k_sobel(
    const float* __restrict__ xg,
    __hip_bfloat16* __restrict__ xh, __hip_bfloat16* __restrict__ xl,
    __hip_bfloat16* __restrict__ yh, __hip_bfloat16* __restrict__ yl)
{
    __shared__ float t[66][66];
    int b = blockIdx.y;
    int n0 = blockIdx.x * 64;
    int tid = threadIdx.x;
    const float* xb = xg + (size_t)b * NN * 64;
    for (int idx = tid; idx < 66 * 64; idx += 256) {
        int r = idx >> 6, c = idx & 63;
        int n = n0 - 1 + r;
        float v = (n >= 0 && n < NN) ? xb[(size_t)n * 64 + c] : 0.f;
        t[r][c + 1] = v;
    }
    for (int idx = tid; idx < 66; idx += 256) { t[idx][0] = 0.f; t[idx][65] = 0.f; }
    __syncthreads();
    int c = tid & 63, rg = tid >> 6;
    int lc = c + 1;
    for (int i = 0; i < 16; ++i) {
        int r = rg * 16 + i;
        float tm1 = t[r][lc - 1],     t0 = t[r][lc],     tp1 = t[r][lc + 1];
        float mm1 = t[r + 1][lc - 1],                    mp1 = t[r + 1][lc + 1];
        float bm1 = t[r + 2][lc - 1], b0 = t[r + 2][lc], bp1 = t[r + 2][lc + 1];
        float gx = (tp1 + 2.f * mp1 + bp1) - (tm1 + 2.f * mm1 + bm1);
        float gy = (bm1 + 2.f * b0 + bp1) - (tm1 + 2.f * t0 + tp1);
        float ax = fabsf(gx), ay = fabsf(gy);
        size_t o = ((size_t)b * NN + n0 + r) * 64 + c;
        __hip_bfloat16 h1 = __float2bfloat16(ax);
        xh[o] = h1;
        xl[o] = __float2bfloat16(ax - __bfloat162float(h1));
        __hip_bfloat16 h2 = __float2bfloat16(ay);
        yh[o] = h2;
        yl[o] = __float2bfloat16(ay - __bfloat162float(h2));
    }
}

// ------- logits v5: 8 waves (512 thr), swapped MFMA (C[m][n]), x LDS dbuf, pipelined -------
// block: n-tile 64 x m-tile 128; wave wv owns m-strip wv*16. grid (32 mt, 64 nt).
__global__ __launch_bounds__(512, 4) void k_logits(
    const __hip_bfloat16* __restrict__ xh_, const __hip_bfloat16* __restrict__ xl_,
    const __hip_bfloat16* __restrict__ yh_, const __hip_bfloat16* __restrict__ yl_,
    __hip_bfloat16* __restrict__ A, float* __restrict__ rowsum)
{
    __shared__ __align__(16) ushort xs[2][2][4096];   // 32 KB; reused as rowsum reduce buf
    const ushort* xh = (const ushort*)xh_;
    const ushort* xl = (const ushort*)xl_;
    const ushort* yh = (const ushort*)yh_;
    const ushort* yl = (const ushort*)yl_;
    int tid = threadIdx.x, lane = tid & 63;
    int wv = __builtin_amdgcn_readfirstlane(tid >> 6);   // 0..7
    int l15 = lane & 15, lg = lane >> 4;
    int m0 = blockIdx.x * 128, n0 = blockIdx.y * 64;

    f32x4 acc[4][4];   // [b][u(n-sub)]
#pragma unroll
    for (int b = 0; b < 4; ++b)
#pragma unroll
        for (int u = 0; u < 4; ++u) acc[b][u] = (f32x4){0.f, 0.f, 0.f, 0.f};

#define STAGEX(buf, b_) do { \
    int ch = tid; \
    int r = ch >> 3; \
    int sc = ((ch & 7) ^ (r & 7)) * 8; \
    gld16(xh + ((size_t)(b_) * NN + n0 + r) * 64 + sc, (char*)xs[buf][0] + ch * 16); \
    gld16(xl + ((size_t)(b_) * NN + n0 + r) * 64 + sc, (char*)xs[buf][1] + ch * 16); \
} while (0)

#define YLOAD(Y, b_) do { \
    size_t rb = ((size_t)(b_) * NN + m0 + wv * 16 + l15) * 64 + lg * 8; \
    Y[0][0] = *(const bf16x8*)(yh + rb); \
    Y[1][0] = *(const bf16x8*)(yh + rb + 32); \
    Y[0][1] = *(const bf16x8*)(yl + rb); \
    Y[1][1] = *(const bf16x8*)(yl + rb + 32); \
} while (0)

#define COMPUTE(buf, Y, b_) do { \
    _Pragma("unroll") \
    for (int ks = 0; ks < 2; ++ks) { \
        bf16x8 xf[4][2]; \
        _Pragma("unroll") \
        for (int u = 0; u < 4; ++u) { \
            int r = u * 16 + l15; \
            int c16 = (ks * 4 + lg) ^ (r & 7); \
            xf[u][0] = *(const bf16x8*)((const char*)xs[buf][0] + r * 128 + c16 * 16); \
            xf[u][1] = *(const bf16x8*)((const char*)xs[buf][1] + r * 128 + c16 * 16); \
        } \
        _Pragma("unroll") \
        for (int u = 0; u < 4; ++u) { \
            f32x4 a = acc[b_][u]; \
            a = __builtin_amdgcn_mfma_f32_16x16x32_bf16(Y[ks][0], xf[u][0], a, 0, 0, 0); \
            a = __builtin_amdgcn_mfma_f32_16x16x32_bf16(Y[ks][0], xf[u][1], a, 0, 0, 0); \
            a = __builtin_amdgcn_mfma_f32_16x16x32_bf16(Y[ks][1], xf[u][0], a, 0, 0, 0); \
            acc[b_][u] = a; \
        } \
    } \
} while (0)

    bf16x8 yA[2][2], yB[2][2];
    STAGEX(0, 0); YLOAD(yA, 0);
    __syncthreads();
    STAGEX(1, 1); YLOAD(yB, 1); COMPUTE(0, yA, 0);
    __syncthreads();
    STAGEX(0, 2); YLOAD(yA, 2); COMPUTE(1, yB, 1);
    __syncthreads();
    STAGEX(1, 3); YLOAD(yB, 3); COMPUTE(0, yA, 2);
    __syncthreads();
    COMPUTE(1, yB, 3);
#undef STAGEX
#undef YLOAD
#undef COMPUTE

    // batch-softmax + packed A store (rows = m, cols = n)
    float rsum[4][4];   // [b][u]
#pragma unroll
    for (int b = 0; b < 4; ++b)
#pragma unroll
        for (int u = 0; u < 4; ++u) rsum[b][u] = 0.f;

#pragma unroll
    for (int u = 0; u < 4; ++u) {
        float av[4][4];
#pragma unroll
        for (int j = 0; j < 4; ++j) {
            float v0 = acc[0][u][j], v1 = acc[1][u][j];
            float v2 = acc[2][u][j], v3 = acc[3][u][j];
            float mx = fmaxf(fmaxf(v0, v1), fmaxf(v2, v3));
            float e0 = __expf(v0 - mx), e1 = __expf(v1 - mx);
            float e2 = __expf(v2 - mx), e3 = __expf(v3 - mx);
            float rz = 1.f / (e0 + e1 + e2 + e3);
            av[0][j] = e0 * rz; av[1][j] = e1 * rz;
            av[2][j] = e2 * rz; av[3][j] = e3 * rz;
            rsum[0][u] += av[0][j]; rsum[1][u] += av[1][j];
            rsum[2][u] += av[2][j]; rsum[3][u] += av[3][j];
        }
        int n = n0 + u * 16 + l15;
        int m = m0 + wv * 16 + lg * 4;
#pragma unroll
        for (int b = 0; b < 4; ++b) {
            uint2 pv;
            pv.x = pk2(av[b][0], av[b][1]);
            pv.y = pk2(av[b][2], av[b][3]);
            *(uint2*)((ushort*)A + (size_t)b * NN * NN + (size_t)n * NN + m) = pv;
        }
    }

    // rowsum: per-wave shuffle reduce -> LDS -> 256 atomics/block
    __syncthreads();   // xs no longer needed
    float* rl = (float*)xs;   // [8][4][64]
#pragma unroll
    for (int b = 0; b < 4; ++b)
#pragma unroll
        for (int u = 0; u < 4; ++u) {
            float s = rsum[b][u];
            s += __shfl_xor(s, 16);
            s += __shfl_xor(s, 32);
            if (lane < 16) rl[((wv * 4) + b) * 64 + u * 16 + lane] = s;
        }
    __syncthreads();
    if (tid < 256) {
        int b = tid >> 6, n = tid & 63;
        float s = 0.f;
#pragma unroll
        for (int w2 = 0; w2 < 8; ++w2) s += rl[(w2 * 4 + b) * 64 + n];
        atomicAdd(&rowsum[(size_t)b * NN + n0 + n], s);
    }
}

__global__ __launch_bounds__(256) void k_dinv(const float* __restrict__ rs, float* __restrict__ dinv)
{
    int i = blockIdx.x * 256 + threadIdx.x;
    dinv[i] = rsqrtf(rs[i] + 1.0f);
}

// ------- small GEMM: t'[m][o] = dinv[m] * sum_c h[m][c] fc[o][c]; write fp32 + bf16^T -------
__global__ __launch_bounds__(256) void k_small(
    const float* __restrict__ h, const float* __restrict__ fc, const float* __restrict__ dinv,
    __hip_bfloat16* __restrict__ tT, float* __restrict__ tf)
{
    int blk = blockIdx.x;
    int b = blk >> 6, m0 = (blk & 63) * 64;
    int tid = threadIdx.x;
    int mi = tid & 63, m = m0 + mi;
    int oq = __builtin_amdgcn_readfirstlane(tid >> 6);
    const float* hr = h + ((size_t)b * NN + m) * 64;
    float hv[64];
#pragma unroll
    for (int i = 0; i < 16; ++i) {
        float4 v = *(const float4*)(hr + 4 * i);
        hv[4 * i] = v.x; hv[4 * i + 1] = v.y; hv[4 * i + 2] = v.z; hv[4 * i + 3] = v.w;
    }
    float dv = dinv[(size_t)b * NN + m];
#pragma unroll
    for (int j = 0; j < 16; ++j) {
        int o = oq * 16 + j;
        const float* wr = fc + (size_t)o * 64;
        float a = 0.f;
#pragma unroll
        for (int c2 = 0; c2 < 64; ++c2) a += hv[c2] * wr[c2];
        a *= dv;
        tf[((size_t)b * NN + m) * 64 + o] = a;
        tT[((size_t)b * 64 + o) * NN + m] = __float2bfloat16(a);
    }
}

// ------- big GEMM v4 (barrier-free, all-register): part[ks][b][n][o] -------
// grid 1024 = ntile(64) x b(4) x ks(4); 4 waves split o; A/B loaded global->reg, dbuf 1 step.
__global__ __launch_bounds__(256, 4) void k_big(
    const __hip_bfloat16* __restrict__ A_, const __hip_bfloat16* __restrict__ tT_,
    float* __restrict__ part)
{
    const ushort* A = (const ushort*)A_;
    const ushort* tT = (const ushort*)tT_;
    int blk = blockIdx.x;
    int ntile = blk & 63, b = (blk >> 6) & 3, ks = blk >> 8;
    int n0 = ntile * 64;
    int tid = threadIdx.x, lane = tid & 63;
    int w = __builtin_amdgcn_readfirstlane(tid >> 6);
    int l15 = lane & 15, lg = lane >> 4;
    size_t kw0 = (size_t)ks * 1024;
    const ushort* Ar = A + (size_t)b * NN * NN + (size_t)(n0 + l15) * NN + kw0 + lg * 8;
    const ushort* Tb = tT + ((size_t)b * 64 + w * 16 + l15) * NN + kw0 + lg * 8;

    f32x4 acc[4];
#pragma unroll
    for (int ti = 0; ti < 4; ++ti) acc[ti] = (f32x4){0.f, 0.f, 0.f, 0.f};

    bf16x8 a0[4][2], a1[4][2], b0[2], b1[2];

#define LOADF(aa, bb, s_) do { \
    _Pragma("unroll") \
    for (int ti = 0; ti < 4; ++ti) \
        _Pragma("unroll") \
        for (int kc = 0; kc < 2; ++kc) \
            (aa)[ti][kc] = *(const bf16x8*)(Ar + (size_t)ti * 16 * NN + (s_) * 64 + kc * 32); \
    _Pragma("unroll") \
    for (int kc = 0; kc < 2; ++kc) \
        (bb)[kc] = *(const bf16x8*)(Tb + (size_t)(s_) * 64 + kc * 32); \
} while (0)
#define MF(aa, bb) do { \
    _Pragma("unroll") \
    for (int kc = 0; kc < 2; ++kc) \
        _Pragma("unroll") \
        for (int ti = 0; ti < 4; ++ti) \
            acc[ti] = __builtin_amdgcn_mfma_f32_16x16x32_bf16((aa)[ti][kc], (bb)[kc], acc[ti], 0, 0, 0); \
} while (0)

    LOADF(a0, b0, 0);
    for (int s = 0; s < 16; s += 2) {
        if (s + 1 < 16) LOADF(a1, b1, s + 1);
        MF(a0, b0);
        if (s + 2 < 16) LOADF(a0, b0, s + 2);
        MF(a1, b1);
    }
#undef LOADF
#undef MF

    float* pp = part + ((size_t)(ks * 4 + b) * NN + n0) * 64;
#pragma unroll
    for (int ti = 0; ti < 4; ++ti)
#pragma unroll
        for (int j = 0; j < 4; ++j)
            pp[(size_t)(ti * 16 + lg * 4 + j) * 64 + w * 16 + l15] = acc[ti][j];
}

// ------- epilogue: sum 4 K-partials + residual, scale by dinv, optional relu -------
__global__ __launch_bounds__(256) void k_red(
    const float* __restrict__ part, const float* __restrict__ tf, const float* __restrict__ dinv,
    float* __restrict__ outp, int relu)
{
    int v = blockIdx.x * 256 + threadIdx.x;
    size_t e0 = (size_t)v * 4;
    int b = (int)(e0 >> 18);
    int n = (int)((e0 >> 6) & (NN - 1));
    f32x4 u = (f32x4){0.f, 0.f, 0.f, 0.f};
#pragma unroll
    for (int s = 0; s < 4; ++s)
        u += *(const f32x4*)(part + (size_t)s * (4 * (size_t)NN * 64) + e0);
    f32x4 t = *(const f32x4*)(tf + e0);
    float dn = dinv[(size_t)b * NN + n];
    f32x4 r;
#pragma unroll
    for (int j = 0; j < 4; ++j) {
        float vv = dn * (u[j] + t[j]);
        if (relu) vv = fmaxf(vv, 0.f);
        r[j] = vv;
    }
    *(f32x4*)(outp + e0) = r;
}

// ------------- bilinear x2 upsample, align_corners; o3 is [b][n][ch] -------------
__global__ __launch_bounds__(256) void k_up(const float* __restrict__ o3, float* __restrict__ outp)
{
    int b = blockIdx.y, Y = blockIdx.x;
    int tid = threadIdx.x;
    int X = tid & 127, cg = tid >> 7;
    int iy = Y * 63; int y0 = iy / 127; float wy = (float)(iy - y0 * 127) * (1.f / 127.f);
    int y1 = min(y0 + 1, 63);
    int ix = X * 63; int x0 = ix / 127; float wx = (float)(ix - x0 * 127) * (1.f / 127.f);
    int x1 = min(x0 + 1, 63);
    const float* p00 = o3 + ((size_t)b * NN + y0 * 64 + x0) * 64;
    const float* p01 = o3 + ((size_t)b * NN + y0 * 64 + x1) * 64;
    const float* p10 = o3 + ((size_t)b * NN + y1 * 64 + x0) * 64;
    const float* p11 = o3 + ((size_t)b * NN + y1 * 64 + x1) * 64;
    float w00 = (1.f - wy) * (1.f - wx), w01 = (1.f - wy) * wx;
    float w10 = wy * (1.f - wx), w11 = wy * wx;
#pragma unroll
    for (int j = 0; j < 32; ++j) {
        int ch = cg * 32 + j;
        float v = w00 * p00[ch] + w01 * p01[ch] + w10 * p10[ch] + w11 * p11[ch];
        outp[(((size_t)b * 64 + ch) * 128 + Y) * 128 + X] = v;
    }
}

extern "C" void kernel_launch(void* const* d_in, const int* in_sizes, int n_in,
                              void* d_out, int out_size, void* d_ws, size_t ws_size,
                              hipStream_t stream)
{
    const float* x   = (const float*)d_in[0];
    const float* cw  = (const float*)d_in[1];
    const float* cb  = (const float*)d_in[2];
    const float* bng = (const float*)d_in[3];
    const float* bnb = (const float*)d_in[4];
    const float* bnm = (const float*)d_in[5];
    const float* bnv = (const float*)d_in[6];
    const float* fc1 = (const float*)d_in[7];
    const float* fc2 = (const float*)d_in[8];
    const float* fc3 = (const float*)d_in[9];
    float* outp = (float*)d_out;

    char* ws = (char*)d_ws;
    size_t off = 0;
    auto alloc = [&](size_t bytes) -> void* {
        void* p = ws + off;
        off += (bytes + 255) & ~(size_t)255;
        return p;
    };
    __hip_bfloat16* Abuf = (__hip_bfloat16*)alloc((size_t)NB * NN * NN * 2);
    float* part   = (float*)alloc((size_t)4 * NB * NN * 64 * 4);
    float* xg     = (float*)alloc((size_t)NB * NN * 64 * 4);
    __hip_bfloat16* sxh = (__hip_bfloat16*)alloc((size_t)NB * NN * 64 * 2);
    __hip_bfloat16* sxl = (__hip_bfloat16*)alloc((size_t)NB * NN * 64 * 2);
    __hip_bfloat16* syh = (__hip_bfloat16*)alloc((size_t)NB * NN * 64 * 2);
    __hip_bfloat16* syl = (__hip_bfloat16*)alloc((size_t)NB * NN * 64 * 2);
    __hip_bfloat16* tT = (__hip_bfloat16*)alloc((size_t)NB * 64 * NN * 2);
    float* tf     = (float*)alloc((size_t)NB * NN * 64 * 4);
    float* h1     = (float*)alloc((size_t)NB * NN * 64 * 4);
    float* h2     = (float*)alloc((size_t)NB * NN * 64 * 4);
    float* o3     = (float*)alloc((size_t)NB * NN * 64 * 4);
    float* rowsum = (float*)alloc((size_t)NB * NN * 4);
    float* dinvb  = (float*)alloc((size_t)NB * NN * 4);
    float* W3     = (float*)alloc((size_t)16 * 64 * 48 * 4);

    hipMemsetAsync(rowsum, 0, (size_t)NB * NN * 4, stream);

    k_wrep<<<144, 256, 0, stream>>>(cw, W3);
    k_conv<<<dim3(64, 4, 4), 256, 0, stream>>>(x, W3, cb, bng, bnb, bnm, bnv, xg);
    k_sobel<<<dim3(64, 4), 256, 0, stream>>>(xg, sxh, sxl, syh, syl);
    k_logits<<<dim3(32, 64), 512, 0, stream>>>(sxh, sxl, syh, syl, Abuf, rowsum);
    k_dinv<<<64, 256, 0, stream>>>(rowsum, dinvb);

    k_small<<<256, 256, 0, stream>>>(xg, fc1, dinvb, tT, tf);
    k_big<<<1024, 256, 0, stream>>>(Abuf, tT, part);
    k_red<<<1024, 256, 0, stream>>>(part, tf, dinvb, h1, 1);

    k_small<<<256, 256, 0, stream>>>(h1, fc2, dinvb, tT, tf);
    k_big<<<1024, 256, 0, stream>>>(Abuf, tT, part);
    k_red<<<1024, 256, 0, stream>>>(part, tf, dinvb, h2, 1);

    k_small<<<256, 256, 0, stream>>>(h2, fc3, dinvb, tT, tf);
    k_big<<<1024, 256, 0, stream>>>(Abuf, tT, part);
    k_red<<<1024, 256, 0, stream>>>(part, tf, dinvb, o3, 0);

    k_up<<<dim3(128, 4), 256, 0, stream>>>(o3, outp);
}

// Round 8
// 377.064 us; speedup vs baseline: 1.3697x; 1.3697x over previous
//
#include <hip/hip_runtime.h>
#include <hip/hip_bf16.h>

typedef float f32x4 __attribute__((ext_vector_type(4)));
typedef short bf16x8 __attribute__((ext_vector_type(8)));

#define NB 4
#define NC 64
#define NH 128
#define NW 128
#define NN 4096
#define BN_EPS_C 1e-5f

__device__ __forceinline__ void gld16(const void* g, void* l) {
    __builtin_amdgcn_global_load_lds((const __attribute__((address_space(1))) void*)g,
                                     (__attribute__((address_space(3))) void*)l, 16, 0, 0);
}
__device__ __forceinline__ unsigned pk2(float a, float b) {
    __hip_bfloat16 x = __float2bfloat16(a), y = __float2bfloat16(b);
    return (unsigned)*(unsigned short*)&x | ((unsigned)*(unsigned short*)&y << 16);
}

#define BAR_NODRAIN asm volatile("s_barrier" ::: "memory")
#define WAIT_VM2    asm volatile("s_waitcnt vmcnt(2)" ::: "memory")

// ------- weight repack: cw[oc][ic][3][3] -> W3[ocg16][ic64][oc4*12+kk] (192B/entry) -------
__global__ __launch_bounds__(256) void k_wrep(const float* __restrict__ cw, float* __restrict__ W3)
{
    int idx = blockIdx.x * 256 + threadIdx.x;   // 16*64*36 = 36864
    if (idx >= 16 * 64 * 36) return;
    int oq = idx / (64 * 36);
    int rem = idx - oq * (64 * 36);
    int ic = rem / 36;
    int j = rem - ic * 36;
    int oc4 = j / 9, kk = j - oc4 * 9;
    W3[((size_t)oq * 64 + ic) * 48 + oc4 * 12 + kk] = cw[(((size_t)(oq * 4 + oc4)) * 64 + ic) * 9 + kk];
}

// ---- conv3x3 s2 p1 + bias + BN + ReLU -> xg[b][n][c]; wave=4 oc, 1024 blocks ----
__global__ __launch_bounds__(256) void k_conv(
    const float* __restrict__ x, const float* __restrict__ W3, const float* __restrict__ cb,
    const float* __restrict__ bng, const float* __restrict__ bnb, const float* __restrict__ bnm,
    const float* __restrict__ bnv, float* __restrict__ xg)
{
    int oh = blockIdx.x, quad = blockIdx.y, b = blockIdx.z;
    int tid = threadIdx.x;
    int ow = tid & 63;
    int w = __builtin_amdgcn_readfirstlane(tid >> 6);
    int ocg = quad * 4 + w;            // 0..15, wave-uniform
    float acc[4] = {0.f, 0.f, 0.f, 0.f};
    const float* xb = x + (size_t)b * NC * NH * NW;
    const float* wbase = W3 + (size_t)ocg * 64 * 48;
    int ih0 = 2 * oh - 1;
    for (int ic = 0; ic < 64; ++ic) {
        const float* xr = xb + (size_t)ic * (NH * NW);
        float v00, v01, v02, v10, v11, v12, v20, v21, v22;
        if (ih0 < 0) { v00 = v01 = v02 = 0.f; }
        else {
            const float* p = xr + ih0 * NW + 2 * ow;
            float2 t = *(const float2*)p;
            v01 = t.x; v02 = t.y;
            v00 = (ow == 0) ? 0.f : p[-1];
        }
        { const float* p = xr + (ih0 + 1) * NW + 2 * ow; float2 t = *(const float2*)p; v11 = t.x; v12 = t.y; v10 = (ow == 0) ? 0.f : p[-1]; }
        { const float* p = xr + (ih0 + 2) * NW + 2 * ow; float2 t = *(const float2*)p; v21 = t.x; v22 = t.y; v20 = (ow == 0) ? 0.f : p[-1]; }
        const float* wp = wbase + ic * 48;   // uniform -> s_loads
#pragma unroll
        for (int j = 0; j < 4; ++j) {
            const float* wj = wp + j * 12;
            acc[j] += wj[0] * v00 + wj[1] * v01 + wj[2] * v02
                    + wj[3] * v10 + wj[4] * v11 + wj[5] * v12
                    + wj[6] * v20 + wj[7] * v21 + wj[8] * v22;
        }
    }
    int n = oh * 64 + ow;
    int oc0 = ocg * 4;
    f32x4 r;
#pragma unroll
    for (int j = 0; j < 4; ++j) {
        int oc = oc0 + j;
        float s = bng[oc] * rsqrtf(bnv[oc] + BN_EPS_C);
        float y = (acc[j] + cb[oc] - bnm[oc]) * s + bnb[oc];
        r[j] = fmaxf(y, 0.f);
    }
    *(f32x4*)(xg + ((size_t)b * NN + n) * 64 + oc0) = r;
}

// ------- sobel |gx|,|gy| over (N, c) image per batch -> split bf16 hi/lo -------
__global__ __launch_bounds__(256) void k_sobel(
    const float* __restrict__ xg,
    __hip_bfloat16* __restrict__ xh, __hip_bfloat16* __restrict__ xl,
    __hip_bfloat16* __restrict__ yh, __hip_bfloat16* __restrict__ yl)
{
    __shared__ float t[66][66];
    int b = blockIdx.y;
    int n0 = blockIdx.x * 64;
    int tid = threadIdx.x;
    const float* xb = xg + (size_t)b * NN * 64;
    for (int idx = tid; idx < 66 * 64; idx += 256) {
        int r = idx >> 6, c = idx & 63;
        int n = n0 - 1 + r;
        float v = (n >= 0 && n < NN) ? xb[(size_t)n * 64 + c] : 0.f;
        t[r][c + 1] = v;
    }
    for (int idx = tid; idx < 66; idx += 256) { t[idx][0] = 0.f; t[idx][65] = 0.f; }
    __syncthreads();
    int c = tid & 63, rg = tid >> 6;
    int lc = c + 1;
    for (int i = 0; i < 16; ++i) {
        int r = rg * 16 + i;
        float tm1 = t[r][lc - 1],     t0 = t[r][lc],     tp1 = t[r][lc + 1];
        float mm1 = t[r + 1][lc - 1],                    mp1 = t[r + 1][lc + 1];
        float bm1 = t[r + 2][lc - 1], b0 = t[r + 2][lc], bp1 = t[r + 2][lc + 1];
        float gx = (tp1 + 2.f * mp1 + bp1) - (tm1 + 2.f * mm1 + bm1);
        float gy = (bm1 + 2.f * b0 + bp1) - (tm1 + 2.f * t0 + tp1);
        float ax = fabsf(gx), ay = fabsf(gy);
        size_t o = ((size_t)b * NN + n0 + r) * 64 + c;
        __hip_bfloat16 h1 = __float2bfloat16(ax);
        xh[o] = h1;
        xl[o] = __float2bfloat16(ax - __bfloat162float(h1));
        __hip_bfloat16 h2 = __float2bfloat16(ay);
        yh[o] = h2;
        yl[o] = __float2bfloat16(ay - __bfloat162float(h2));
    }
}

// ------- logits v5: 8 waves (512 thr), swapped MFMA (C[m][n]), x LDS dbuf, pipelined -------
__global__ __launch_bounds__(512, 4) void k_logits(
    const __hip_bfloat16* __restrict__ xh_, const __hip_bfloat16* __restrict__ xl_,
    const __hip_bfloat16* __restrict__ yh_, const __hip_bfloat16* __restrict__ yl_,
    __hip_bfloat16* __restrict__ A, float* __restrict__ rowsum)
{
    __shared__ __align__(16) ushort xs[2][2][4096];   // 32 KB; reused as rowsum reduce buf
    const ushort* xh = (const ushort*)xh_;
    const ushort* xl = (const ushort*)xl_;
    const ushort* yh = (const ushort*)yh_;
    const ushort* yl = (const ushort*)yl_;
    int tid = threadIdx.x, lane = tid & 63;
    int wv = __builtin_amdgcn_readfirstlane(tid >> 6);   // 0..7
    int l15 = lane & 15, lg = lane >> 4;
    int m0 = blockIdx.x * 128, n0 = blockIdx.y * 64;

    f32x4 acc[4][4];   // [b][u(n-sub)]
#pragma unroll
    for (int b = 0; b < 4; ++b)
#pragma unroll
        for (int u = 0; u < 4; ++u) acc[b][u] = (f32x4){0.f, 0.f, 0.f, 0.f};

#define STAGEX(buf, b_) do { \
    int ch = tid; \
    int r = ch >> 3; \
    int sc = ((ch & 7) ^ (r & 7)) * 8; \
    gld16(xh + ((size_t)(b_) * NN + n0 + r) * 64 + sc, (char*)xs[buf][0] + ch * 16); \
    gld16(xl + ((size_t)(b_) * NN + n0 + r) * 64 + sc, (char*)xs[buf][1] + ch * 16); \
} while (0)

#define YLOAD(Y, b_) do { \
    size_t rb = ((size_t)(b_) * NN + m0 + wv * 16 + l15) * 64 + lg * 8; \
    Y[0][0] = *(const bf16x8*)(yh + rb); \
    Y[1][0] = *(const bf16x8*)(yh + rb + 32); \
    Y[0][1] = *(const bf16x8*)(yl + rb); \
    Y[1][1] = *(const bf16x8*)(yl + rb + 32); \
} while (0)

#define COMPUTE(buf, Y, b_) do { \
    _Pragma("unroll") \
    for (int ks = 0; ks < 2; ++ks) { \
        bf16x8 xf[4][2]; \
        _Pragma("unroll") \
        for (int u = 0; u < 4; ++u) { \
            int r = u * 16 + l15; \
            int c16 = (ks * 4 + lg) ^ (r & 7); \
            xf[u][0] = *(const bf16x8*)((const char*)xs[buf][0] + r * 128 + c16 * 16); \
            xf[u][1] = *(const bf16x8*)((const char*)xs[buf][1] + r * 128 + c16 * 16); \
        } \
        _Pragma("unroll") \
        for (int u = 0; u < 4; ++u) { \
            f32x4 a = acc[b_][u]; \
            a = __builtin_amdgcn_mfma_f32_16x16x32_bf16(Y[ks][0], xf[u][0], a, 0, 0, 0); \
            a = __builtin_amdgcn_mfma_f32_16x16x32_bf16(Y[ks][0], xf[u][1], a, 0, 0, 0); \
            a = __builtin_amdgcn_mfma_f32_16x16x32_bf16(Y[ks][1], xf[u][0], a, 0, 0, 0); \
            acc[b_][u] = a; \
        } \
    } \
} while (0)

    bf16x8 yA[2][2], yB[2][2];
    STAGEX(0, 0); YLOAD(yA, 0);
    __syncthreads();
    STAGEX(1, 1); YLOAD(yB, 1); COMPUTE(0, yA, 0);
    __syncthreads();
    STAGEX(0, 2); YLOAD(yA, 2); COMPUTE(1, yB, 1);
    __syncthreads();
    STAGEX(1, 3); YLOAD(yB, 3); COMPUTE(0, yA, 2);
    __syncthreads();
    COMPUTE(1, yB, 3);
#undef STAGEX
#undef YLOAD
#undef COMPUTE

    // batch-softmax + packed A store (rows = m, cols = n)
    float rsum[4][4];   // [b][u]
#pragma unroll
    for (int b = 0; b < 4; ++b)
#pragma unroll
        for (int u = 0; u < 4; ++u) rsum[b][u] = 0.f;

#pragma unroll
    for (int u = 0; u < 4; ++u) {
        float av[4][4];
#pragma unroll
        for (int j = 0; j < 4; ++j) {
            float v0 = acc[0][u][j], v1 = acc[1][u][j];
            float v2 = acc[2][u][j], v3 = acc[3][u][j];
            float mx = fmaxf(fmaxf(v0, v1), fmaxf(v2, v3));
            float e0 = __expf(v0 - mx), e1 = __expf(v1 - mx);
            float e2 = __expf(v2 - mx), e3 = __expf(v3 - mx);
            float rz = 1.f / (e0 + e1 + e2 + e3);
            av[0][j] = e0 * rz; av[1][j] = e1 * rz;
            av[2][j] = e2 * rz; av[3][j] = e3 * rz;
            rsum[0][u] += av[0][j]; rsum[1][u] += av[1][j];
            rsum[2][u] += av[2][j]; rsum[3][u] += av[3][j];
        }
        int n = n0 + u * 16 + l15;
        int m = m0 + wv * 16 + lg * 4;
#pragma unroll
        for (int b = 0; b < 4; ++b) {
            uint2 pv;
            pv.x = pk2(av[b][0], av[b][1]);
            pv.y = pk2(av[b][2], av[b][3]);
            *(uint2*)((ushort*)A + (size_t)b * NN * NN + (size_t)n * NN + m) = pv;
        }
    }

    // rowsum: per-wave shuffle reduce -> LDS -> 256 atomics/block
    __syncthreads();   // xs no longer needed
    float* rl = (float*)xs;   // [8][4][64]
#pragma unroll
    for (int b = 0; b < 4; ++b)
#pragma unroll
        for (int u = 0; u < 4; ++u) {
            float s = rsum[b][u];
            s += __shfl_xor(s, 16);
            s += __shfl_xor(s, 32);
            if (lane < 16) rl[((wv * 4) + b) * 64 + u * 16 + lane] = s;
        }
    __syncthreads();
    if (tid < 256) {
        int b = tid >> 6, n = tid & 63;
        float s = 0.f;
#pragma unroll
        for (int w2 = 0; w2 < 8; ++w2) s += rl[(w2 * 4 + b) * 64 + n];
        atomicAdd(&rowsum[(size_t)b * NN + n0 + n], s);
    }
}

__global__ __launch_bounds__(256) void k_dinv(const float* __restrict__ rs, float* __restrict__ dinv)
{
    int i = blockIdx.x * 256 + threadIdx.x;
    dinv[i] = rsqrtf(rs[i] + 1.0f);
}

// ------- small GEMM: t'[m][o] = dinv[m] * sum_c h[m][c] fc[o][c]; write fp32 + bf16^T -------
__global__ __launch_bounds__(256) void k_small(
    const float* __restrict__ h, const float* __restrict__ fc, const float* __restrict__ dinv,
    __hip_bfloat16* __restrict__ tT, float* __restrict__ tf)
{
    int blk = blockIdx.x;
    int b = blk >> 6, m0 = (blk & 63) * 64;
    int tid = threadIdx.x;
    int mi = tid & 63, m = m0 + mi;
    int oq = __builtin_amdgcn_readfirstlane(tid >> 6);
    const float* hr = h + ((size_t)b * NN + m) * 64;
    float hv[64];
#pragma unroll
    for (int i = 0; i < 16; ++i) {
        float4 v = *(const float4*)(hr + 4 * i);
        hv[4 * i] = v.x; hv[4 * i + 1] = v.y; hv[4 * i + 2] = v.z; hv[4 * i + 3] = v.w;
    }
    float dv = dinv[(size_t)b * NN + m];
#pragma unroll
    for (int j = 0; j < 16; ++j) {
        int o = oq * 16 + j;
        const float* wr = fc + (size_t)o * 64;
        float a = 0.f;
#pragma unroll
        for (int c2 = 0; c2 < 64; ++c2) a += hv[c2] * wr[c2];
        a *= dv;
        tf[((size_t)b * NN + m) * 64 + o] = a;
        tT[((size_t)b * 64 + o) * NN + m] = __float2bfloat16(a);
    }
}

// ------- big GEMM v5: LDS dbuf + counted vmcnt (no drain) -------
// grid 1024 = ntile(64) x b(4) x ks(4); 4 waves split o; A staged via gld16.
__global__ __launch_bounds__(256, 4) void k_big(
    const __hip_bfloat16* __restrict__ A_, const __hip_bfloat16* __restrict__ tT_,
    float* __restrict__ part)
{
    __shared__ __align__(16) ushort ab[2][4096];
    const ushort* A = (const ushort*)A_;
    const ushort* tT = (const ushort*)tT_;
    int blk = blockIdx.x;
    int ntile = blk & 63, b = (blk >> 6) & 3, ks = blk >> 8;
    int n0 = ntile * 64;
    int tid = threadIdx.x, lane = tid & 63;
    int w = __builtin_amdgcn_readfirstlane(tid >> 6);
    int l15 = lane & 15, lg = lane >> 4;
    size_t kw0 = (size_t)ks * 1024;
    const ushort* Ab = A + (size_t)b * NN * NN;
    const ushort* Tb = tT + ((size_t)b * 64 + w * 16 + l15) * NN + kw0;

    f32x4 acc[4];
#pragma unroll
    for (int ti = 0; ti < 4; ++ti) acc[ti] = (f32x4){0.f, 0.f, 0.f, 0.f};

#define STAGE(buf, s) do { \
    _Pragma("unroll") \
    for (int p = 0; p < 2; ++p) { \
        int ch = p * 256 + tid; \
        int r = ch >> 3; \
        int sc = ((ch & 7) ^ (r & 7)) * 8; \
        gld16(Ab + (size_t)(n0 + r) * NN + kw0 + (size_t)(s) * 64 + sc, (char*)ab[buf] + ch * 16); \
    } \
} while (0)

    // prologue: stage0 [2], tb0 [2], stage1 [2] -> wait 4 oldest (stage0+tb0)
    STAGE(0, 0);
    bf16x8 bf0 = *(const bf16x8*)(Tb + lg * 8);
    bf16x8 bf1 = *(const bf16x8*)(Tb + 32 + lg * 8);
    STAGE(1, 1);
    WAIT_VM2;
    BAR_NODRAIN;

    int cur = 0;
    for (int s = 0; s < 16; ++s) {
        int sn = (s + 1 < 16) ? s + 1 : 15;
        bf16x8 nf0 = *(const bf16x8*)(Tb + (size_t)sn * 64 + lg * 8);
        bf16x8 nf1 = *(const bf16x8*)(Tb + (size_t)sn * 64 + 32 + lg * 8);
        // compute on ab[cur] with bf regs (step s)
#pragma unroll
        for (int kc = 0; kc < 2; ++kc) {
            bf16x8 bfr = (kc == 0) ? bf0 : bf1;
#pragma unroll
            for (int ti = 0; ti < 4; ++ti) {
                int r = ti * 16 + l15;
                int c16 = (kc * 4 + lg) ^ (r & 7);
                bf16x8 afr = *(const bf16x8*)((const char*)ab[cur] + r * 128 + c16 * 16);
                acc[ti] = __builtin_amdgcn_mfma_f32_16x16x32_bf16(afr, bfr, acc[ti], 0, 0, 0);
            }
        }
        BAR_NODRAIN;                       // all waves done reading ab[cur]
        int s2 = (s + 2 < 16) ? s + 2 : 15;
        STAGE(cur, s2);                    // refill cur (dummy at tail, overwritten after reads)
        WAIT_VM2;                          // stage(s+1)+tb(s+1) landed; stage(s+2) in flight
        BAR_NODRAIN;                       // publish stage(s+1) across waves
        bf0 = nf0; bf1 = nf1;
        cur ^= 1;
    }
#undef STAGE

    float* pp = part + ((size_t)(ks * 4 + b) * NN + n0) * 64;
#pragma unroll
    for (int ti = 0; ti < 4; ++ti)
#pragma unroll
        for (int j = 0; j < 4; ++j)
            pp[(size_t)(ti * 16 + lg * 4 + j) * 64 + w * 16 + l15] = acc[ti][j];
}

// ------- epilogue: sum 4 K-partials + residual, scale by dinv, optional relu -------
__global__ __launch_bounds__(256) void k_red(
    const float* __restrict__ part, const float* __restrict__ tf, const float* __restrict__ dinv,
    float* __restrict__ outp, int relu)
{
    int v = blockIdx.x * 256 + threadIdx.x;
    size_t e0 = (size_t)v * 4;
    int b = (int)(e0 >> 18);
    int n = (int)((e0 >> 6) & (NN - 1));
    f32x4 u = (f32x4){0.f, 0.f, 0.f, 0.f};
#pragma unroll
    for (int s = 0; s < 4; ++s)
        u += *(const f32x4*)(part + (size_t)s * (4 * (size_t)NN * 64) + e0);
    f32x4 t = *(const f32x4*)(tf + e0);
    float dn = dinv[(size_t)b * NN + n];
    f32x4 r;
#pragma unroll
    for (int j = 0; j < 4; ++j) {
        float vv = dn * (u[j] + t[j]);
        if (relu) vv = fmaxf(vv, 0.f);
        r[j] = vv;
    }
    *(f32x4*)(outp + e0) = r;
}

// ------------- bilinear x2 upsample, align_corners; o3 is [b][n][ch] -------------
__global__ __launch_bounds__(256) void k_up(const float* __restrict__ o3, float* __restrict__ outp)
{
    int b = blockIdx.y, Y = blockIdx.x;
    int tid = threadIdx.x;
    int X = tid & 127, cg = tid >> 7;
    int iy = Y * 63; int y0 = iy / 127; float wy = (float)(iy - y0 * 127) * (1.f / 127.f);
    int y1 = min(y0 + 1, 63);
    int ix = X * 63; int x0 = ix / 127; float wx = (float)(ix - x0 * 127) * (1.f / 127.f);
    int x1 = min(x0 + 1, 63);
    const float* p00 = o3 + ((size_t)b * NN + y0 * 64 + x0) * 64;
    const float* p01 = o3 + ((size_t)b * NN + y0 * 64 + x1) * 64;
    const float* p10 = o3 + ((size_t)b * NN + y1 * 64 + x0) * 64;
    const float* p11 = o3 + ((size_t)b * NN + y1 * 64 + x1) * 64;
    float w00 = (1.f - wy) * (1.f - wx), w01 = (1.f - wy) * wx;
    float w10 = wy * (1.f - wx), w11 = wy * wx;
#pragma unroll
    for (int j = 0; j < 32; ++j) {
        int ch = cg * 32 + j;
        float v = w00 * p00[ch] + w01 * p01[ch] + w10 * p10[ch] + w11 * p11[ch];
        outp[(((size_t)b * 64 + ch) * 128 + Y) * 128 + X] = v;
    }
}

extern "C" void kernel_launch(void* const* d_in, const int* in_sizes, int n_in,
                              void* d_out, int out_size, void* d_ws, size_t ws_size,
                              hipStream_t stream)
{
    const float* x   = (const float*)d_in[0];
    const float* cw  = (const float*)d_in[1];
    const float* cb  = (const float*)d_in[2];
    const float* bng = (const float*)d_in[3];
    const float* bnb = (const float*)d_in[4];
    const float* bnm = (const float*)d_in[5];
    const float* bnv = (const float*)d_in[6];
    const float* fc1 = (const float*)d_in[7];
    const float* fc2 = (const float*)d_in[8];
    const float* fc3 = (const float*)d_in[9];
    float* outp = (float*)d_out;

    char* ws = (char*)d_ws;
    size_t off = 0;
    auto alloc = [&](size_t bytes) -> void* {
        void* p = ws + off;
        off += (bytes + 255) & ~(size_t)255;
        return p;
    };
    __hip_bfloat16* Abuf = (__hip_bfloat16*)alloc((size_t)NB * NN * NN * 2);
    float* part   = (float*)alloc((size_t)4 * NB * NN * 64 * 4);
    float* xg     = (float*)alloc((size_t)NB * NN * 64 * 4);
    __hip_bfloat16* sxh = (__hip_bfloat16*)alloc((size_t)NB * NN * 64 * 2);
    __hip_bfloat16* sxl = (__hip_bfloat16*)alloc((size_t)NB * NN * 64 * 2);
    __hip_bfloat16* syh = (__hip_bfloat16*)alloc((size_t)NB * NN * 64 * 2);
    __hip_bfloat16* syl = (__hip_bfloat16*)alloc((size_t)NB * NN * 64 * 2);
    __hip_bfloat16* tT = (__hip_bfloat16*)alloc((size_t)NB * 64 * NN * 2);
    float* tf     = (float*)alloc((size_t)NB * NN * 64 * 4);
    float* h1     = (float*)alloc((size_t)NB * NN * 64 * 4);
    float* h2     = (float*)alloc((size_t)NB * NN * 64 * 4);
    float* o3     = (float*)alloc((size_t)NB * NN * 64 * 4);
    float* rowsum = (float*)alloc((size_t)NB * NN * 4);
    float* dinvb  = (float*)alloc((size_t)NB * NN * 4);
    float* W3     = (float*)alloc((size_t)16 * 64 * 48 * 4);

    hipMemsetAsync(rowsum, 0, (size_t)NB * NN * 4, stream);

    k_wrep<<<144, 256, 0, stream>>>(cw, W3);
    k_conv<<<dim3(64, 4, 4), 256, 0, stream>>>(x, W3, cb, bng, bnb, bnm, bnv, xg);
    k_sobel<<<dim3(64, 4), 256, 0, stream>>>(xg, sxh, sxl, syh, syl);
    k_logits<<<dim3(32, 64), 512, 0, stream>>>(sxh, sxl, syh, syl, Abuf, rowsum);
    k_dinv<<<64, 256, 0, stream>>>(rowsum, dinvb);

    k_small<<<256, 256, 0, stream>>>(xg, fc1, dinvb, tT, tf);
    k_big<<<1024, 256, 0, stream>>>(Abuf, tT, part);
    k_red<<<1024, 256, 0, stream>>>(part, tf, dinvb, h1, 1);

    k_small<<<256, 256, 0, stream>>>(h1, fc2, dinvb, tT, tf);
    k_big<<<1024, 256, 0, stream>>>(Abuf, tT, part);
    k_red<<<1024, 256, 0, stream>>>(part, tf, dinvb, h2, 1);

    k_small<<<256, 256, 0, stream>>>(h2, fc3, dinvb, tT, tf);
    k_big<<<1024, 256, 0, stream>>>(Abuf, tT, part);
    k_red<<<1024, 256, 0, stream>>>(part, tf, dinvb, o3, 0);

    k_up<<<dim3(128, 4), 256, 0, stream>>>(o3, outp);
}